// Round 2
// baseline (3163.481 us; speedup 1.0000x reference)
//
#include <hip/hip_runtime.h>

// ---------------------------------------------------------------- encoder
__global__ __launch_bounds__(256) void encoder_kernel(
    const float* __restrict__ xc, const float* __restrict__ yc, const float* __restrict__ xt,
    const float* __restrict__ W1, const float* __restrict__ b1,
    const float* __restrict__ W2, const float* __restrict__ b2,
    float* __restrict__ z)
{
  __shared__ float zin[10];
  __shared__ float hid[256];
  int blk = blockIdx.x; int b = blk>>10; int t = blk & 1023;
  int tid = threadIdx.x;
  if (tid < 10){
    float v;
    if (tid < 8)      v = (t<512) ? xc[((size_t)b*512+t)*8+tid] : xt[((size_t)b*512+(t-512))*8+tid];
    else if (tid==8)  v = (t<512) ? yc[(size_t)b*512+t] : 0.f;
    else              v = (t<512) ? 0.f : 1.f;
    zin[tid]=v;
  }
  __syncthreads();
  float s = b1[tid];
  #pragma unroll
  for (int i=0;i<10;i++) s += zin[i]*W1[i*256+tid];
  hid[tid] = fmaxf(s, 0.f);
  __syncthreads();
  float o = b2[tid];
  for (int j=0;j<256;j++) o += hid[j]*W2[j*256+tid];
  z[((size_t)b*1024+t)*256 + tid] = o;
}

// ---------------------------------------------------------------- layernorm
__global__ __launch_bounds__(256) void ln_fast(const float* __restrict__ z,
    const float* __restrict__ g, const float* __restrict__ be, float* __restrict__ h)
{
  __shared__ float red[256];
  int row = blockIdx.x, tid = threadIdx.x;
  float x = z[(size_t)row*256 + tid];
  red[tid] = x; __syncthreads();
  for (int s=128; s>0; s>>=1){ if (tid<s) red[tid]+=red[tid+s]; __syncthreads(); }
  float mu = red[0] * (1.f/256.f); __syncthreads();
  float d = x - mu;
  red[tid] = d*d; __syncthreads();
  for (int s=128; s>0; s>>=1){ if (tid<s) red[tid]+=red[tid+s]; __syncthreads(); }
  float var = red[0] * (1.f/256.f);
  float r = rsqrtf(var + 1e-5f);
  h[(size_t)row*256+tid] = d*r*g[tid] + be[tid];
}

// ---------------------------------------------------------------- tiled f32 GEMM
// out[M x N] = EPI(A[M x K] @ B[K x N] + bias)
// EPI 0: plain ; 1: relu ; 2: + resid (out may alias resid)
// 64x64 tile / block, 4x4 micro-tile / thread, K-slice 16.
template<int EPI>
__global__ __launch_bounds__(256) void gemm_f32(
    const float* __restrict__ A, const float* __restrict__ B,
    const float* __restrict__ bias, const float* __restrict__ resid,
    float* __restrict__ out, int N, int K)
{
  __shared__ float As[16][68];
  __shared__ float Bs[16][68];
  const int tid = threadIdx.x;
  const int tx = tid & 15, ty = tid >> 4;
  const int m0 = blockIdx.y*64, n0 = blockIdx.x*64;
  const int am = tid >> 2, ak = (tid & 3) * 4;
  const int bk = tid >> 4, bn = (tid & 15) * 4;
  float acc[4][4] = {};
  for (int kk = 0; kk < K; kk += 16){
    float4 av = *(const float4*)&A[(size_t)(m0+am)*K + kk + ak];
    float4 bv = *(const float4*)&B[(size_t)(kk+bk)*N + n0 + bn];
    __syncthreads();
    As[ak+0][am]=av.x; As[ak+1][am]=av.y; As[ak+2][am]=av.z; As[ak+3][am]=av.w;
    *(float4*)&Bs[bk][bn] = bv;
    __syncthreads();
    #pragma unroll
    for (int k=0;k<16;k++){
      float4 a = *(const float4*)&As[k][ty*4];
      float4 b = *(const float4*)&Bs[k][tx*4];
      float ar[4] = {a.x,a.y,a.z,a.w};
      float br[4] = {b.x,b.y,b.z,b.w};
      #pragma unroll
      for (int i=0;i<4;i++)
        #pragma unroll
        for (int j=0;j<4;j++)
          acc[i][j] += ar[i]*br[j];
    }
  }
  const int gc0 = n0 + tx*4;
  float4 bsv = *(const float4*)&bias[gc0];
  float bb[4] = {bsv.x,bsv.y,bsv.z,bsv.w};
  #pragma unroll
  for (int i=0;i<4;i++){
    int gr = m0 + ty*4 + i;
    size_t off = (size_t)gr*N + gc0;
    float4 o;
    float v0=acc[i][0]+bb[0], v1=acc[i][1]+bb[1], v2=acc[i][2]+bb[2], v3=acc[i][3]+bb[3];
    if (EPI==1){ v0=fmaxf(v0,0.f); v1=fmaxf(v1,0.f); v2=fmaxf(v2,0.f); v3=fmaxf(v3,0.f); }
    if (EPI==2){ float4 rv = *(const float4*)&resid[off]; v0+=rv.x; v1+=rv.y; v2+=rv.z; v3+=rv.w; }
    o.x=v0; o.y=v1; o.z=v2; o.w=v3;
    *(float4*)&out[off] = o;
  }
}

// ---------------------------------------------------------------- attention v4
// 16 lanes per q-row: 4-way dim split (quad, xor 1/2 completes the 32-dot)
// x 4-way key split (key quarter kh owns keys [kh*128, kh*128+128)).
// Each key quarter runs an independent online-softmax state; states merged
// in-register after the loop with two shfl_xor levels (xor 4, xor 8).
// 4x the wave count of v3 -> occupancy saturates the 32-wave/CU cap
// (v3 was grid-limited at 16 waves/CU, 58% stall).
// qkv: [nb][1024][768] f32 (q|k|v each 256). Keys 0..511 for all rows; target
// rows (q>=512 <=> blockIdx.x>=32 at 16 q/block) also self-attend (kh==3 only).
__global__ __launch_bounds__(256) void attn_v4(
    const float* __restrict__ qkv, float* __restrict__ o)
{
  const int tid = threadIdx.x;
  const int ld  = tid & 3;         // dim-slice within quad: dims [ld*8, ld*8+8)
  const int kh  = (tid >> 2) & 3;  // key quarter: keys [kh*128, kh*128+128)
  const int qi  = tid >> 4;        // 0..15 : q-row within block
  const int qblk = blockIdx.x, h = blockIdx.y, b = blockIdx.z;
  const int q = qblk*16 + qi;
  const float* base = qkv + (size_t)b*1024*768;
  const int doff = h*32 + ld*8;
  const float sc = 0.17677669529663687f;   // 1/sqrt(32)

  float Q[8];
  {
    const float4* qp = (const float4*)&base[(size_t)q*768 + doff];
    float4 t0 = qp[0], t1 = qp[1];
    Q[0]=t0.x*sc; Q[1]=t0.y*sc; Q[2]=t0.z*sc; Q[3]=t0.w*sc;
    Q[4]=t1.x*sc; Q[5]=t1.y*sc; Q[6]=t1.z*sc; Q[7]=t1.w*sc;
  }
  float m = -1e30f, l = 0.f;
  float acc[8];
  #pragma unroll
  for (int d=0; d<8; d++) acc[d]=0.f;

  const int j0 = kh*128;
  for (int jj=0; jj<128; jj+=4){
    const int j = j0 + jj;
    const float4* k0 = (const float4*)&base[(size_t)(j+0)*768 + 256 + doff];
    const float4* k1 = (const float4*)&base[(size_t)(j+1)*768 + 256 + doff];
    const float4* k2 = (const float4*)&base[(size_t)(j+2)*768 + 256 + doff];
    const float4* k3 = (const float4*)&base[(size_t)(j+3)*768 + 256 + doff];
    float4 a0=k0[0], c0=k0[1];
    float4 a1=k1[0], c1=k1[1];
    float4 a2=k2[0], c2=k2[1];
    float4 a3=k3[0], c3=k3[1];
    float d0 = Q[0]*a0.x+Q[1]*a0.y+Q[2]*a0.z+Q[3]*a0.w
             + Q[4]*c0.x+Q[5]*c0.y+Q[6]*c0.z+Q[7]*c0.w;
    float d1 = Q[0]*a1.x+Q[1]*a1.y+Q[2]*a1.z+Q[3]*a1.w
             + Q[4]*c1.x+Q[5]*c1.y+Q[6]*c1.z+Q[7]*c1.w;
    float d2 = Q[0]*a2.x+Q[1]*a2.y+Q[2]*a2.z+Q[3]*a2.w
             + Q[4]*c2.x+Q[5]*c2.y+Q[6]*c2.z+Q[7]*c2.w;
    float d3 = Q[0]*a3.x+Q[1]*a3.y+Q[2]*a3.z+Q[3]*a3.w
             + Q[4]*c3.x+Q[5]*c3.y+Q[6]*c3.z+Q[7]*c3.w;
    // complete the 32-dim dot across the quad (xor 1, xor 2 stay in-quad)
    d0 += __shfl_xor(d0,1); d0 += __shfl_xor(d0,2);
    d1 += __shfl_xor(d1,1); d1 += __shfl_xor(d1,2);
    d2 += __shfl_xor(d2,1); d2 += __shfl_xor(d2,2);
    d3 += __shfl_xor(d3,1); d3 += __shfl_xor(d3,2);
    float mn = fmaxf(fmaxf(fmaxf(d0,d1),fmaxf(d2,d3)), m);
    float corr = __expf(m - mn);
    float p0 = __expf(d0-mn), p1 = __expf(d1-mn), p2 = __expf(d2-mn), p3 = __expf(d3-mn);
    l = l*corr + (p0+p1+p2+p3);
    const float4* v0 = (const float4*)&base[(size_t)(j+0)*768 + 512 + doff];
    const float4* v1 = (const float4*)&base[(size_t)(j+1)*768 + 512 + doff];
    const float4* v2 = (const float4*)&base[(size_t)(j+2)*768 + 512 + doff];
    const float4* v3 = (const float4*)&base[(size_t)(j+3)*768 + 512 + doff];
    float4 e0=v0[0], f0=v0[1];
    float4 e1=v1[0], f1=v1[1];
    float4 e2=v2[0], f2=v2[1];
    float4 e3=v3[0], f3=v3[1];
    acc[0] = acc[0]*corr + p0*e0.x + p1*e1.x + p2*e2.x + p3*e3.x;
    acc[1] = acc[1]*corr + p0*e0.y + p1*e1.y + p2*e2.y + p3*e3.y;
    acc[2] = acc[2]*corr + p0*e0.z + p1*e1.z + p2*e2.z + p3*e3.z;
    acc[3] = acc[3]*corr + p0*e0.w + p1*e1.w + p2*e2.w + p3*e3.w;
    acc[4] = acc[4]*corr + p0*f0.x + p1*f1.x + p2*f2.x + p3*f3.x;
    acc[5] = acc[5]*corr + p0*f0.y + p1*f1.y + p2*f2.y + p3*f3.y;
    acc[6] = acc[6]*corr + p0*f0.z + p1*f1.z + p2*f2.z + p3*f3.z;
    acc[7] = acc[7]*corr + p0*f0.w + p1*f1.w + p2*f2.w + p3*f3.w;
    m = mn;
  }
  // self-attend (target rows only, counted once: key quarter 3)
  if (qblk >= 32 && kh == 3){
    const float4* kp = (const float4*)&base[(size_t)q*768 + 256 + doff];
    float4 a=kp[0], c=kp[1];
    float d0 = Q[0]*a.x+Q[1]*a.y+Q[2]*a.z+Q[3]*a.w
             + Q[4]*c.x+Q[5]*c.y+Q[6]*c.z+Q[7]*c.w;
    d0 += __shfl_xor(d0,1); d0 += __shfl_xor(d0,2);
    float mn = fmaxf(m, d0);
    float corr = __expf(m - mn);
    float p0 = __expf(d0 - mn);
    l = l*corr + p0;
    const float4* vp = (const float4*)&base[(size_t)q*768 + 512 + doff];
    float4 e=vp[0], f=vp[1];
    acc[0]=acc[0]*corr + p0*e.x; acc[1]=acc[1]*corr + p0*e.y;
    acc[2]=acc[2]*corr + p0*e.z; acc[3]=acc[3]*corr + p0*e.w;
    acc[4]=acc[4]*corr + p0*f.x; acc[5]=acc[5]*corr + p0*f.y;
    acc[6]=acc[6]*corr + p0*f.z; acc[7]=acc[7]*corr + p0*f.w;
    m = mn;
  }
  // merge the 4 key-quarter online-softmax states (xor 4, then xor 8)
  #pragma unroll
  for (int s=4; s<=8; s<<=1){
    float m2 = __shfl_xor(m, s);
    float l2 = __shfl_xor(l, s);
    float mn = fmaxf(m, m2);
    float c1 = __expf(m - mn), c2 = __expf(m2 - mn);
    l = l*c1 + l2*c2;
    #pragma unroll
    for (int d=0; d<8; d++){
      float a2 = __shfl_xor(acc[d], s);
      acc[d] = acc[d]*c1 + a2*c2;
    }
    m = mn;
  }
  if (kh == 0){
    float inv = 1.f/l;
    float* op = o + ((size_t)b*1024 + q)*256 + doff;
    float4 t0, t1;
    t0.x=acc[0]*inv; t0.y=acc[1]*inv; t0.z=acc[2]*inv; t0.w=acc[3]*inv;
    t1.x=acc[4]*inv; t1.y=acc[5]*inv; t1.z=acc[6]*inv; t1.w=acc[7]*inv;
    *(float4*)&op[0] = t0;
    *(float4*)&op[4] = t1;
  }
}

// ---------------------------------------------------------------- launch
extern "C" void kernel_launch(void* const* d_in, const int* in_sizes, int n_in,
                              void* d_out, int out_size, void* d_ws, size_t ws_size,
                              hipStream_t stream)
{
  (void)in_sizes; (void)n_in; (void)out_size;
  const float* xc   = (const float*)d_in[0];
  const float* yc   = (const float*)d_in[1];
  const float* xt   = (const float*)d_in[2];
  const float* eW1  = (const float*)d_in[3];
  const float* eb1  = (const float*)d_in[4];
  const float* eW2  = (const float*)d_in[5];
  const float* eb2  = (const float*)d_in[6];
  const float* Wqkv = (const float*)d_in[7];
  const float* bqkv = (const float*)d_in[8];
  const float* Wo   = (const float*)d_in[9];
  const float* bo   = (const float*)d_in[10];
  const float* ln1g = (const float*)d_in[11];
  const float* ln1b = (const float*)d_in[12];
  const float* ln2g = (const float*)d_in[13];
  const float* ln2b = (const float*)d_in[14];
  const float* Wff1 = (const float*)d_in[15];
  const float* bff1 = (const float*)d_in[16];
  const float* Wff2 = (const float*)d_in[17];
  const float* bff2 = (const float*)d_in[18];

  float* zf = (float*)d_out;            // residual stream [8][1024][256] f32 = 8 MB
  char* ws = (char*)d_ws;
  float* hb      = (float*)(ws);                        // 8 MB (LN out / attn out)
  float* scratch = (float*)(ws + (size_t)8*1024*1024);  // qkv / ffh

  const bool bigws = (ws_size == 0) || (ws_size >= (size_t)33*1024*1024);

  encoder_kernel<<<8192, 256, 0, stream>>>(xc, yc, xt, eW1, eb1, eW2, eb2, zf);

  for (int l=0; l<6; l++){
    const float* Wq = Wqkv + (size_t)l*256*768;
    const float* Wl = Wo   + (size_t)l*256*256;
    const float* W1 = Wff1 + (size_t)l*256*1024;
    const float* W2 = Wff2 + (size_t)l*1024*256;

    ln_fast<<<8192, 256, 0, stream>>>(zf, ln1g+l*256, ln1b+l*256, hb);
    if (bigws){
      // full-batch: qkv = 24 MB scratch
      gemm_f32<0><<<dim3(12,128), 256, 0, stream>>>(hb, Wq, bqkv+l*768,
                                                    nullptr, scratch, 768, 256);
      attn_v4<<<dim3(64,8,8), 256, 0, stream>>>(scratch, hb);   // hb consumed by gemm above
    } else {
      for (int c=0; c<4; c++){           // 2 batches per chunk (6 MB scratch)
        float* hrows = hb + (size_t)c*2048*256;
        gemm_f32<0><<<dim3(12,32), 256, 0, stream>>>(hrows, Wq, bqkv+l*768,
                                                     nullptr, scratch, 768, 256);
        attn_v4<<<dim3(64,8,2), 256, 0, stream>>>(scratch, hrows);
      }
    }
    gemm_f32<2><<<dim3(4,128), 256, 0, stream>>>(hb, Wl, bo+l*256, zf, zf, 256, 256);

    ln_fast<<<8192, 256, 0, stream>>>(zf, ln2g+l*256, ln2b+l*256, hb);
    if (bigws){
      for (int c=0; c<2; c++){           // 4-batch FF chunks (ffh 16 MB scratch)
        float* hrows = hb + (size_t)c*4096*256;
        float* zrows = zf + (size_t)c*4096*256;
        gemm_f32<1><<<dim3(16,64), 256, 0, stream>>>(hrows, W1, bff1+l*1024,
                                                     nullptr, scratch, 1024, 256);
        gemm_f32<2><<<dim3(4,64), 256, 0, stream>>>(scratch, W2, bff2+l*256,
                                                    zrows, zrows, 256, 1024);
      }
    } else {
      for (int c=0; c<4; c++){           // 2-batch FF chunks (ffh 8 MB scratch)
        float* hrows = hb + (size_t)c*2048*256;
        float* zrows = zf + (size_t)c*2048*256;
        gemm_f32<1><<<dim3(16,32), 256, 0, stream>>>(hrows, W1, bff1+l*1024,
                                                     nullptr, scratch, 1024, 256);
        gemm_f32<2><<<dim3(4,32), 256, 0, stream>>>(scratch, W2, bff2+l*256,
                                                    zrows, zrows, 256, 1024);
      }
    }
  }
}

// Round 3
// 2460.534 us; speedup vs baseline: 1.2857x; 1.2857x over previous
//
#include <hip/hip_runtime.h>

// ---------------------------------------------------------------- encoder
__global__ __launch_bounds__(256) void encoder_kernel(
    const float* __restrict__ xc, const float* __restrict__ yc, const float* __restrict__ xt,
    const float* __restrict__ W1, const float* __restrict__ b1,
    const float* __restrict__ W2, const float* __restrict__ b2,
    float* __restrict__ z)
{
  __shared__ float zin[10];
  __shared__ float hid[256];
  int blk = blockIdx.x; int b = blk>>10; int t = blk & 1023;
  int tid = threadIdx.x;
  if (tid < 10){
    float v;
    if (tid < 8)      v = (t<512) ? xc[((size_t)b*512+t)*8+tid] : xt[((size_t)b*512+(t-512))*8+tid];
    else if (tid==8)  v = (t<512) ? yc[(size_t)b*512+t] : 0.f;
    else              v = (t<512) ? 0.f : 1.f;
    zin[tid]=v;
  }
  __syncthreads();
  float s = b1[tid];
  #pragma unroll
  for (int i=0;i<10;i++) s += zin[i]*W1[i*256+tid];
  hid[tid] = fmaxf(s, 0.f);
  __syncthreads();
  float o = b2[tid];
  for (int j=0;j<256;j++) o += hid[j]*W2[j*256+tid];
  z[((size_t)b*1024+t)*256 + tid] = o;
}

// ---------------------------------------------------------------- layernorm
__global__ __launch_bounds__(256) void ln_fast(const float* __restrict__ z,
    const float* __restrict__ g, const float* __restrict__ be, float* __restrict__ h)
{
  __shared__ float red[256];
  int row = blockIdx.x, tid = threadIdx.x;
  float x = z[(size_t)row*256 + tid];
  red[tid] = x; __syncthreads();
  for (int s=128; s>0; s>>=1){ if (tid<s) red[tid]+=red[tid+s]; __syncthreads(); }
  float mu = red[0] * (1.f/256.f); __syncthreads();
  float d = x - mu;
  red[tid] = d*d; __syncthreads();
  for (int s=128; s>0; s>>=1){ if (tid<s) red[tid]+=red[tid+s]; __syncthreads(); }
  float var = red[0] * (1.f/256.f);
  float r = rsqrtf(var + 1e-5f);
  h[(size_t)row*256+tid] = d*r*g[tid] + be[tid];
}

// ---------------------------------------------------------------- tiled f32 GEMM
// out[M x N] = EPI(A[M x K] @ B[K x N] + bias)
// EPI 0: plain ; 1: relu ; 2: + resid (out may alias resid)
// 64x64 tile / block, 4x4 micro-tile / thread, K-slice 16.
template<int EPI>
__global__ __launch_bounds__(256) void gemm_f32(
    const float* __restrict__ A, const float* __restrict__ B,
    const float* __restrict__ bias, const float* __restrict__ resid,
    float* __restrict__ out, int N, int K)
{
  __shared__ float As[16][68];
  __shared__ float Bs[16][68];
  const int tid = threadIdx.x;
  const int tx = tid & 15, ty = tid >> 4;
  const int m0 = blockIdx.y*64, n0 = blockIdx.x*64;
  const int am = tid >> 2, ak = (tid & 3) * 4;
  const int bk = tid >> 4, bn = (tid & 15) * 4;
  float acc[4][4] = {};
  for (int kk = 0; kk < K; kk += 16){
    float4 av = *(const float4*)&A[(size_t)(m0+am)*K + kk + ak];
    float4 bv = *(const float4*)&B[(size_t)(kk+bk)*N + n0 + bn];
    __syncthreads();
    As[ak+0][am]=av.x; As[ak+1][am]=av.y; As[ak+2][am]=av.z; As[ak+3][am]=av.w;
    *(float4*)&Bs[bk][bn] = bv;
    __syncthreads();
    #pragma unroll
    for (int k=0;k<16;k++){
      float4 a = *(const float4*)&As[k][ty*4];
      float4 b = *(const float4*)&Bs[k][tx*4];
      float ar[4] = {a.x,a.y,a.z,a.w};
      float br[4] = {b.x,b.y,b.z,b.w};
      #pragma unroll
      for (int i=0;i<4;i++)
        #pragma unroll
        for (int j=0;j<4;j++)
          acc[i][j] += ar[i]*br[j];
    }
  }
  const int gc0 = n0 + tx*4;
  float4 bsv = *(const float4*)&bias[gc0];
  float bb[4] = {bsv.x,bsv.y,bsv.z,bsv.w};
  #pragma unroll
  for (int i=0;i<4;i++){
    int gr = m0 + ty*4 + i;
    size_t off = (size_t)gr*N + gc0;
    float4 o;
    float v0=acc[i][0]+bb[0], v1=acc[i][1]+bb[1], v2=acc[i][2]+bb[2], v3=acc[i][3]+bb[3];
    if (EPI==1){ v0=fmaxf(v0,0.f); v1=fmaxf(v1,0.f); v2=fmaxf(v2,0.f); v3=fmaxf(v3,0.f); }
    if (EPI==2){ float4 rv = *(const float4*)&resid[off]; v0+=rv.x; v1+=rv.y; v2+=rv.z; v3+=rv.w; }
    o.x=v0; o.y=v1; o.z=v2; o.w=v3;
    *(float4*)&out[off] = o;
  }
}

// ---------------------------------------------------------------- attention v5
// One thread = one full (q,h) row; Q[32] and acc[32] in registers.
// Whole K/V head-slice (512 keys x 32 dims x 2) staged once in LDS (128 KB).
// All lanes of a wave process the same key in lockstep -> every LDS read is a
// same-address broadcast (conflict-free); the 32-dot is entirely in-lane:
// ZERO cross-lane ops and ZERO global loads in the inner loop (v4 was bound by
// the 2-shuffles-per-key dep chain, not occupancy).
// Block = 512 threads: tid<256 -> keys 0..255 (kg0), tid>=256 -> keys 256..511
// (kg1), same 256 q-rows; the two online-softmax halves merge through LDS.
// Grid = (4 qgroups, 8 h, 8 b) = 256 blocks = 1 block/CU (2 waves/SIMD).
// Targets (q>=512 <=> qg>=2) self-attend; handled once by kg1.
__global__ __launch_bounds__(512, 2) void attn_v5(
    const float* __restrict__ qkv, float* __restrict__ o)
{
  __shared__ float Ks[512*32];   // 64 KB
  __shared__ float Vs[512*32];   // 64 KB
  const int tid = threadIdx.x;
  const int qg = blockIdx.x, h = blockIdx.y, b = blockIdx.z;
  const int qi = tid & 255;
  const int kg = tid >> 8;             // 0: keys 0..255, 1: keys 256..511
  const int q  = qg*256 + qi;
  const float* base = qkv + (size_t)b*1024*768;
  const int hoff = h*32;
  const float sc = 0.17677669529663687f;   // 1/sqrt(32)

  // ---- stage K,V (all 512 keys) into LDS, coalesced (8 lanes x 16B per row)
  #pragma unroll
  for (int t = 0; t < 8; ++t){
    int i = tid + t*512;               // 0..4095
    int row = i >> 3, c4 = (i & 7)*4;
    *(float4*)&Ks[row*32 + c4] = *(const float4*)&base[(size_t)row*768 + 256 + hoff + c4];
  }
  #pragma unroll
  for (int t = 0; t < 8; ++t){
    int i = tid + t*512;
    int row = i >> 3, c4 = (i & 7)*4;
    *(float4*)&Vs[row*32 + c4] = *(const float4*)&base[(size_t)row*768 + 512 + hoff + c4];
  }

  // ---- load Q (scaled)
  float Q[32];
  {
    const float4* qp = (const float4*)&base[(size_t)q*768 + hoff];
    #pragma unroll
    for (int p=0;p<8;p++){
      float4 t = qp[p];
      Q[p*4+0]=t.x*sc; Q[p*4+1]=t.y*sc; Q[p*4+2]=t.z*sc; Q[p*4+3]=t.w*sc;
    }
  }
  __syncthreads();

  float m = -1e30f, l = 0.f;
  float acc[32];
  #pragma unroll
  for (int d=0;d<32;d++) acc[d]=0.f;

  const int j0 = kg*256;
  for (int jj=0; jj<256; jj+=2){
    const float* k0 = &Ks[(j0+jj)*32];
    const float* k1 = &Ks[(j0+jj+1)*32];
    float s00=0.f,s01=0.f,s02=0.f,s03=0.f, s10=0.f,s11=0.f,s12=0.f,s13=0.f;
    #pragma unroll
    for (int p=0;p<8;p++){
      float4 a = *(const float4*)&k0[p*4];
      float4 c = *(const float4*)&k1[p*4];
      s00 += Q[p*4+0]*a.x; s01 += Q[p*4+1]*a.y;
      s02 += Q[p*4+2]*a.z; s03 += Q[p*4+3]*a.w;
      s10 += Q[p*4+0]*c.x; s11 += Q[p*4+1]*c.y;
      s12 += Q[p*4+2]*c.z; s13 += Q[p*4+3]*c.w;
    }
    float d0 = (s00+s01)+(s02+s03);
    float d1 = (s10+s11)+(s12+s13);
    float mn = fmaxf(m, fmaxf(d0,d1));
    float corr = __expf(m-mn);
    float p0 = __expf(d0-mn), p1 = __expf(d1-mn);
    l = l*corr + p0 + p1;
    const float* v0 = &Vs[(j0+jj)*32];
    const float* v1 = &Vs[(j0+jj+1)*32];
    #pragma unroll
    for (int p=0;p<8;p++){
      float4 e = *(const float4*)&v0[p*4];
      float4 f = *(const float4*)&v1[p*4];
      acc[p*4+0] = acc[p*4+0]*corr + p0*e.x + p1*f.x;
      acc[p*4+1] = acc[p*4+1]*corr + p0*e.y + p1*f.y;
      acc[p*4+2] = acc[p*4+2]*corr + p0*e.z + p1*f.z;
      acc[p*4+3] = acc[p*4+3]*corr + p0*e.w + p1*f.w;
    }
    m = mn;
  }

  // ---- self-attend (targets only; counted once, by kg1)
  if (kg==1 && q >= 512){
    const float4* kp = (const float4*)&base[(size_t)q*768 + 256 + hoff];
    float s0=0.f,s1=0.f,s2=0.f,s3=0.f;
    #pragma unroll
    for (int p=0;p<8;p++){
      float4 t = kp[p];
      s0 += Q[p*4+0]*t.x; s1 += Q[p*4+1]*t.y;
      s2 += Q[p*4+2]*t.z; s3 += Q[p*4+3]*t.w;
    }
    float d0 = (s0+s1)+(s2+s3);
    float mn = fmaxf(m, d0);
    float corr = __expf(m-mn);
    float p0 = __expf(d0-mn);
    l = l*corr + p0;
    const float4* vp = (const float4*)&base[(size_t)q*768 + 512 + hoff];
    #pragma unroll
    for (int p=0;p<8;p++){
      float4 e = vp[p];
      acc[p*4+0]=acc[p*4+0]*corr + p0*e.x;
      acc[p*4+1]=acc[p*4+1]*corr + p0*e.y;
      acc[p*4+2]=acc[p*4+2]*corr + p0*e.z;
      acc[p*4+3]=acc[p*4+3]*corr + p0*e.w;
    }
    m = mn;
  }

  // ---- merge the two key-halves through LDS (reuse Ks; all reads done)
  __syncthreads();
  if (kg==1){
    float* pp = &Ks[(size_t)qi*36];
    #pragma unroll
    for (int d=0;d<32;d++) pp[d]=acc[d];
    pp[32]=m; pp[33]=l;
  }
  __syncthreads();
  if (kg==0){
    const float* pp = &Ks[(size_t)qi*36];
    float m2 = pp[32], l2 = pp[33];
    float mn = fmaxf(m, m2);
    float c1 = __expf(m-mn), c2 = __expf(m2-mn);
    float inv = 1.f/(l*c1 + l2*c2);
    float* op = o + ((size_t)b*1024 + q)*256 + hoff;
    #pragma unroll
    for (int p=0;p<8;p++){
      float4 t;
      t.x = (acc[p*4+0]*c1 + pp[p*4+0]*c2)*inv;
      t.y = (acc[p*4+1]*c1 + pp[p*4+1]*c2)*inv;
      t.z = (acc[p*4+2]*c1 + pp[p*4+2]*c2)*inv;
      t.w = (acc[p*4+3]*c1 + pp[p*4+3]*c2)*inv;
      *(float4*)&op[p*4] = t;
    }
  }
}

// ---------------------------------------------------------------- launch
extern "C" void kernel_launch(void* const* d_in, const int* in_sizes, int n_in,
                              void* d_out, int out_size, void* d_ws, size_t ws_size,
                              hipStream_t stream)
{
  (void)in_sizes; (void)n_in; (void)out_size;
  const float* xc   = (const float*)d_in[0];
  const float* yc   = (const float*)d_in[1];
  const float* xt   = (const float*)d_in[2];
  const float* eW1  = (const float*)d_in[3];
  const float* eb1  = (const float*)d_in[4];
  const float* eW2  = (const float*)d_in[5];
  const float* eb2  = (const float*)d_in[6];
  const float* Wqkv = (const float*)d_in[7];
  const float* bqkv = (const float*)d_in[8];
  const float* Wo   = (const float*)d_in[9];
  const float* bo   = (const float*)d_in[10];
  const float* ln1g = (const float*)d_in[11];
  const float* ln1b = (const float*)d_in[12];
  const float* ln2g = (const float*)d_in[13];
  const float* ln2b = (const float*)d_in[14];
  const float* Wff1 = (const float*)d_in[15];
  const float* bff1 = (const float*)d_in[16];
  const float* Wff2 = (const float*)d_in[17];
  const float* bff2 = (const float*)d_in[18];

  float* zf = (float*)d_out;            // residual stream [8][1024][256] f32 = 8 MB
  char* ws = (char*)d_ws;
  float* hb      = (float*)(ws);                        // 8 MB (LN out / attn out)
  float* scratch = (float*)(ws + (size_t)8*1024*1024);  // qkv / ffh

  const bool bigws = (ws_size == 0) || (ws_size >= (size_t)33*1024*1024);

  encoder_kernel<<<8192, 256, 0, stream>>>(xc, yc, xt, eW1, eb1, eW2, eb2, zf);

  for (int l=0; l<6; l++){
    const float* Wq = Wqkv + (size_t)l*256*768;
    const float* Wl = Wo   + (size_t)l*256*256;
    const float* W1 = Wff1 + (size_t)l*256*1024;
    const float* W2 = Wff2 + (size_t)l*1024*256;

    ln_fast<<<8192, 256, 0, stream>>>(zf, ln1g+l*256, ln1b+l*256, hb);
    if (bigws){
      // full-batch: qkv = 24 MB scratch
      gemm_f32<0><<<dim3(12,128), 256, 0, stream>>>(hb, Wq, bqkv+l*768,
                                                    nullptr, scratch, 768, 256);
      attn_v5<<<dim3(4,8,8), 512, 0, stream>>>(scratch, hb);   // hb consumed by gemm above
    } else {
      for (int c=0; c<4; c++){           // 2 batches per chunk (6 MB scratch)
        float* hrows = hb + (size_t)c*2048*256;
        gemm_f32<0><<<dim3(12,32), 256, 0, stream>>>(hrows, Wq, bqkv+l*768,
                                                     nullptr, scratch, 768, 256);
        attn_v5<<<dim3(4,8,2), 512, 0, stream>>>(scratch, hrows);
      }
    }
    gemm_f32<2><<<dim3(4,128), 256, 0, stream>>>(hb, Wl, bo+l*256, zf, zf, 256, 256);

    ln_fast<<<8192, 256, 0, stream>>>(zf, ln2g+l*256, ln2b+l*256, hb);
    if (bigws){
      for (int c=0; c<2; c++){           // 4-batch FF chunks (ffh 16 MB scratch)
        float* hrows = hb + (size_t)c*4096*256;
        float* zrows = zf + (size_t)c*4096*256;
        gemm_f32<1><<<dim3(16,64), 256, 0, stream>>>(hrows, W1, bff1+l*1024,
                                                     nullptr, scratch, 1024, 256);
        gemm_f32<2><<<dim3(4,64), 256, 0, stream>>>(scratch, W2, bff2+l*256,
                                                    zrows, zrows, 256, 1024);
      }
    } else {
      for (int c=0; c<4; c++){           // 2-batch FF chunks (ffh 8 MB scratch)
        float* hrows = hb + (size_t)c*2048*256;
        float* zrows = zf + (size_t)c*2048*256;
        gemm_f32<1><<<dim3(16,32), 256, 0, stream>>>(hrows, W1, bff1+l*1024,
                                                     nullptr, scratch, 1024, 256);
        gemm_f32<2><<<dim3(4,32), 256, 0, stream>>>(scratch, W2, bff2+l*256,
                                                    zrows, zrows, 256, 1024);
      }
    }
  }
}